// Round 2
// baseline (41.571 us; speedup 1.0000x reference)
//
#include <hip/hip_runtime.h>
#include <math.h>

// Shapes (NCHW, f32):
//  x1: (8,128,128,128) -> maxpool2 -> (8,128,64,64), tiled x2   in C
//  x2: (8, 32,256,256) -> maxpool4 -> (8, 32,64,64), tiled x8   in C
//  x3: (8,  2,512,512) -> maxpool8 -> (8,  2,64,64), tiled x128 in C
//  ff : (8,256,64,64)
//  out = relu(y1 + y2 + y3 + ff), (8,256,64,64)
//
// R1: grid 512 -> 2048 (split each output row into 4 w-quarters of 16).
// 8 blocks/CU -> 32 waves/CU to fix the latency-bound 21%-of-HBM profile.
// Every tensor still read exactly once (w-split is disjoint everywhere).

__global__ __launch_bounds__(256, 8) void fused_ff_block3(
    const float* __restrict__ x1, const float* __restrict__ x2,
    const float* __restrict__ x3, const float* __restrict__ ff,
    float* __restrict__ out)
{
    __shared__ float y2s[32][16];   // 2 KiB
    __shared__ float y3s[2][16];    // 128 B

    const int bid = blockIdx.x;
    const int wq  = bid & 3;        // w-quarter: 16 output cols
    const int h   = (bid >> 2) & 63;
    const int b   = bid >> 8;
    const int tid = threadIdx.x;

    // ---- Phase 1 loads: y3 (8x8 pool of x3). 8 lanes per output, 1 row each.
    const int lane = tid & 63;
    const int o3   = (tid >> 6) * 8 + (lane >> 3);  // 0..31 = c3*16 + w
    const int r3   = lane & 7;                      // pool row
    const int c3   = o3 >> 4;
    const int w3   = o3 & 15;
    const float* p3 = x3 + (size_t)b * 524288 + (size_t)c3 * 262144
                    + (size_t)(h * 8 + r3) * 512 + (size_t)(wq * 16 + w3) * 8;
    const float4 a3 = *reinterpret_cast<const float4*>(p3);
    const float4 b3 = *reinterpret_cast<const float4*>(p3 + 4);

    // ---- Phase 2: y2 (4x4 pool of x2), 2 outputs/thread, independent loads.
    #pragma unroll
    for (int it = 0; it < 2; ++it) {
        const int v  = tid + it * 256;      // 0..511
        const int c2 = v >> 4;              // 0..31
        const int w2 = v & 15;
        const float* p = x2 + (size_t)b * 2097152 + (size_t)c2 * 65536
                       + (size_t)(h * 4) * 256 + (size_t)(wq * 16 + w2) * 4;
        const float4 q0 = *reinterpret_cast<const float4*>(p);
        const float4 q1 = *reinterpret_cast<const float4*>(p + 256);
        const float4 q2 = *reinterpret_cast<const float4*>(p + 512);
        const float4 q3 = *reinterpret_cast<const float4*>(p + 768);
        float m = fmaxf(fmaxf(fmaxf(q0.x, q0.y), fmaxf(q0.z, q0.w)),
                        fmaxf(fmaxf(q1.x, q1.y), fmaxf(q1.z, q1.w)));
        m = fmaxf(m, fmaxf(fmaxf(q2.x, q2.y), fmaxf(q2.z, q2.w)));
        m = fmaxf(m, fmaxf(fmaxf(q3.x, q3.y), fmaxf(q3.z, q3.w)));
        y2s[c2][w2] = m;
    }

    // ---- Phase 1 reduce: fold 8 rows across lanes (xor 1,2,4 over r3).
    float m3 = fmaxf(fmaxf(fmaxf(a3.x, a3.y), fmaxf(a3.z, a3.w)),
                     fmaxf(fmaxf(b3.x, b3.y), fmaxf(b3.z, b3.w)));
    m3 = fmaxf(m3, __shfl_xor(m3, 1, 64));
    m3 = fmaxf(m3, __shfl_xor(m3, 2, 64));
    m3 = fmaxf(m3, __shfl_xor(m3, 4, 64));
    if (r3 == 0) y3s[c3][w3] = m3;

    __syncthreads();

    // ---- Phase 3: 2x2 pool of x1 in regs (float4 of outputs along w);
    //      combine + relu; write channels c1 and c1+128.
    const int w4  = tid & 3;        // which float4 along the 16-w quarter
    const int c1b = tid >> 2;       // 0..63
    #pragma unroll
    for (int it = 0; it < 2; ++it) {
        const int c1 = c1b + it * 64;       // 0..127
        const float* p = x1 + (size_t)b * 2097152 + (size_t)c1 * 16384
                       + (size_t)(h * 2) * 128 + (size_t)(wq * 16 + w4 * 4) * 2;
        const float4 a0 = *reinterpret_cast<const float4*>(p);
        const float4 a1 = *reinterpret_cast<const float4*>(p + 4);
        const float4 r0 = *reinterpret_cast<const float4*>(p + 128);
        const float4 r1 = *reinterpret_cast<const float4*>(p + 132);
        float4 y1v;
        y1v.x = fmaxf(fmaxf(a0.x, a0.y), fmaxf(r0.x, r0.y));
        y1v.y = fmaxf(fmaxf(a0.z, a0.w), fmaxf(r0.z, r0.w));
        y1v.z = fmaxf(fmaxf(a1.x, a1.y), fmaxf(r1.x, r1.y));
        y1v.w = fmaxf(fmaxf(a1.z, a1.w), fmaxf(r1.z, r1.w));

        const float4 y2v = *reinterpret_cast<const float4*>(&y2s[c1 & 31][w4 * 4]);
        const float4 y3v = *reinterpret_cast<const float4*>(&y3s[c1 & 1][w4 * 4]);

        const size_t o0 = (size_t)b * 1048576 + (size_t)c1 * 4096
                        + (size_t)h * 64 + (size_t)(wq * 16 + w4 * 4);
        const size_t o1 = o0 + (size_t)128 * 4096;
        const float4 f0 = *reinterpret_cast<const float4*>(ff + o0);
        const float4 f1 = *reinterpret_cast<const float4*>(ff + o1);

        float4 s;
        s.x = y1v.x + y2v.x + y3v.x;
        s.y = y1v.y + y2v.y + y3v.y;
        s.z = y1v.z + y2v.z + y3v.z;
        s.w = y1v.w + y2v.w + y3v.w;

        float4 u0, u1;
        u0.x = fmaxf(s.x + f0.x, 0.0f);
        u0.y = fmaxf(s.y + f0.y, 0.0f);
        u0.z = fmaxf(s.z + f0.z, 0.0f);
        u0.w = fmaxf(s.w + f0.w, 0.0f);
        u1.x = fmaxf(s.x + f1.x, 0.0f);
        u1.y = fmaxf(s.y + f1.y, 0.0f);
        u1.z = fmaxf(s.z + f1.z, 0.0f);
        u1.w = fmaxf(s.w + f1.w, 0.0f);

        *reinterpret_cast<float4*>(out + o0) = u0;
        *reinterpret_cast<float4*>(out + o1) = u1;
    }
}

extern "C" void kernel_launch(void* const* d_in, const int* in_sizes, int n_in,
                              void* d_out, int out_size, void* d_ws, size_t ws_size,
                              hipStream_t stream) {
    const float* x1 = (const float*)d_in[0];
    const float* x2 = (const float*)d_in[1];
    const float* x3 = (const float*)d_in[2];
    const float* ff = (const float*)d_in[3];
    float* out = (float*)d_out;

    dim3 grid(2048);  // 8 b * 64 h * 4 w-quarters
    dim3 block(256);
    fused_ff_block3<<<grid, block, 0, stream>>>(x1, x2, x3, ff, out);
}

// Round 3
// 40.360 us; speedup vs baseline: 1.0300x; 1.0300x over previous
//
#include <hip/hip_runtime.h>
#include <math.h>

// Shapes (NCHW, f32):
//  x1: (8,128,128,128) -> maxpool2 -> (8,128,64,64), tiled x2   in C
//  x2: (8, 32,256,256) -> maxpool4 -> (8, 32,64,64), tiled x8   in C
//  x3: (8,  2,512,512) -> maxpool8 -> (8,  2,64,64), tiled x128 in C
//  ff : (8,256,64,64)
//  out = relu(y1 + y2 + y3 + ff), (8,256,64,64)
//
// R2: back to R0's data partition (block = (b, h), full 64-w rows -> 90 MB
// FETCH), but 1024-thread blocks: 512 blocks x 16 waves = 32 waves/CU.
// ~10 independent float4 loads in flight per thread before the barrier.
// LDS rows padded to 68 floats (272 B: 16B-aligned, +4 banks/row) to kill
// the 4-way read conflict in the combine phase.

__global__ __launch_bounds__(1024, 8) void fused_ff_block3(
    const float* __restrict__ x1, const float* __restrict__ x2,
    const float* __restrict__ x3, const float* __restrict__ ff,
    float* __restrict__ out)
{
    __shared__ float y2s[32][68];   // 8.5 KiB
    __shared__ float y3s[2][68];

    const int bid = blockIdx.x;
    const int b   = bid >> 6;       // 0..7
    const int h   = bid & 63;       // output row
    const int tid = threadIdx.x;    // 0..1023

    // ---- y3: 8x8 pool of x3. 8 threads per output (1 row each), shfl fold.
    {
        const int o3 = tid >> 3;    // 0..127 = c3*64 + w
        const int r3 = tid & 7;     // pool row (lane bits 0..2)
        const int c3 = o3 >> 6;
        const int w3 = o3 & 63;
        const float* p = x3 + (size_t)b * 524288 + (size_t)c3 * 262144
                       + (size_t)(h * 8 + r3) * 512 + (size_t)w3 * 8;
        const float4 a = *reinterpret_cast<const float4*>(p);
        const float4 c = *reinterpret_cast<const float4*>(p + 4);
        float m = fmaxf(fmaxf(fmaxf(a.x, a.y), fmaxf(a.z, a.w)),
                        fmaxf(fmaxf(c.x, c.y), fmaxf(c.z, c.w)));
        m = fmaxf(m, __shfl_xor(m, 1, 64));
        m = fmaxf(m, __shfl_xor(m, 2, 64));
        m = fmaxf(m, __shfl_xor(m, 4, 64));
        if (r3 == 0) y3s[c3][w3] = m;
    }

    // ---- y2: 4x4 pool of x2, 2 outputs/thread, 8 independent float4 loads.
    #pragma unroll
    for (int it = 0; it < 2; ++it) {
        const int v  = tid + it * 1024;     // 0..2047
        const int c2 = v >> 6;              // 0..31
        const int w2 = v & 63;
        const float* p = x2 + (size_t)b * 2097152 + (size_t)c2 * 65536
                       + (size_t)(h * 4) * 256 + (size_t)w2 * 4;
        const float4 q0 = *reinterpret_cast<const float4*>(p);
        const float4 q1 = *reinterpret_cast<const float4*>(p + 256);
        const float4 q2 = *reinterpret_cast<const float4*>(p + 512);
        const float4 q3 = *reinterpret_cast<const float4*>(p + 768);
        float m = fmaxf(fmaxf(fmaxf(q0.x, q0.y), fmaxf(q0.z, q0.w)),
                        fmaxf(fmaxf(q1.x, q1.y), fmaxf(q1.z, q1.w)));
        m = fmaxf(m, fmaxf(fmaxf(q2.x, q2.y), fmaxf(q2.z, q2.w)));
        m = fmaxf(m, fmaxf(fmaxf(q3.x, q3.y), fmaxf(q3.z, q3.w)));
        y2s[c2][w2] = m;
    }

    __syncthreads();

    // ---- 2x2 pool of x1 in regs (float4 of outputs along w); combine +
    //      relu; write channels c1 and c1+128 (x1 read exactly once).
    const int w4  = tid & 15;       // which float4 along the 64-w row
    const int c10 = tid >> 4;       // 0..63
    #pragma unroll
    for (int it = 0; it < 2; ++it) {
        const int c1 = c10 + it * 64;       // 0..127
        const float* p = x1 + (size_t)b * 2097152 + (size_t)c1 * 16384
                       + (size_t)(h * 2) * 128 + (size_t)w4 * 8;
        const float4 a0 = *reinterpret_cast<const float4*>(p);
        const float4 a1 = *reinterpret_cast<const float4*>(p + 4);
        const float4 r0 = *reinterpret_cast<const float4*>(p + 128);
        const float4 r1 = *reinterpret_cast<const float4*>(p + 132);
        float4 y1v;
        y1v.x = fmaxf(fmaxf(a0.x, a0.y), fmaxf(r0.x, r0.y));
        y1v.y = fmaxf(fmaxf(a0.z, a0.w), fmaxf(r0.z, r0.w));
        y1v.z = fmaxf(fmaxf(a1.x, a1.y), fmaxf(r1.x, r1.y));
        y1v.w = fmaxf(fmaxf(a1.z, a1.w), fmaxf(r1.z, r1.w));

        const float4 y2v = *reinterpret_cast<const float4*>(&y2s[c1 & 31][w4 * 4]);
        const float4 y3v = *reinterpret_cast<const float4*>(&y3s[c1 & 1][w4 * 4]);

        const size_t o0 = (size_t)b * 1048576 + (size_t)c1 * 4096
                        + (size_t)h * 64 + (size_t)w4 * 4;
        const size_t o1 = o0 + (size_t)128 * 4096;
        const float4 f0 = *reinterpret_cast<const float4*>(ff + o0);
        const float4 f1 = *reinterpret_cast<const float4*>(ff + o1);

        float4 s;
        s.x = y1v.x + y2v.x + y3v.x;
        s.y = y1v.y + y2v.y + y3v.y;
        s.z = y1v.z + y2v.z + y3v.z;
        s.w = y1v.w + y2v.w + y3v.w;

        float4 u0, u1;
        u0.x = fmaxf(s.x + f0.x, 0.0f);
        u0.y = fmaxf(s.y + f0.y, 0.0f);
        u0.z = fmaxf(s.z + f0.z, 0.0f);
        u0.w = fmaxf(s.w + f0.w, 0.0f);
        u1.x = fmaxf(s.x + f1.x, 0.0f);
        u1.y = fmaxf(s.y + f1.y, 0.0f);
        u1.z = fmaxf(s.z + f1.z, 0.0f);
        u1.w = fmaxf(s.w + f1.w, 0.0f);

        *reinterpret_cast<float4*>(out + o0) = u0;
        *reinterpret_cast<float4*>(out + o1) = u1;
    }
}

extern "C" void kernel_launch(void* const* d_in, const int* in_sizes, int n_in,
                              void* d_out, int out_size, void* d_ws, size_t ws_size,
                              hipStream_t stream) {
    const float* x1 = (const float*)d_in[0];
    const float* x2 = (const float*)d_in[1];
    const float* x3 = (const float*)d_in[2];
    const float* ff = (const float*)d_in[3];
    float* out = (float*)d_out;

    dim3 grid(512);   // 8 b * 64 h
    dim3 block(1024);
    fused_ff_block3<<<grid, block, 0, stream>>>(x1, x2, x3, ff, out);
}

// Round 4
// 37.601 us; speedup vs baseline: 1.1056x; 1.0734x over previous
//
#include <hip/hip_runtime.h>
#include <math.h>

// Shapes (NCHW, f32):
//  x1: (8,128,128,128)  -> maxpool2 -> (8,128,64,64), tiled x2  in C
//  x2: (8, 32,256,256)  -> maxpool4 -> (8, 32,64,64), tiled x8  in C
//  x3: (8,  2,512,512)  -> maxpool8 -> (8,  2,64,64), tiled x128 in C
//  ff : (8,256,64,64)
//  out = relu(y1 + y2 + y3 + ff), (8,256,64,64)
//
// R3 = R0 (best bench: 36.5 us) + NON-TEMPORAL output stores.
// Model: bench time ~= HBM_bytes / 3.4 TB/s (R0->R1 dur ratio == HBM-bytes
// ratio to 3 decimal places). Output writes (32 MB/replay, read only once
// at validation) pollute L3 and evict input lines (inputs 176 MB vs L3 256
// MB). `nt` stores keep the write stream out of the cache hierarchy ->
// higher steady-state input residency -> lower steady FETCH -> lower dur.

__global__ __launch_bounds__(256) void fused_ff_block3(
    const float* __restrict__ x1, const float* __restrict__ x2,
    const float* __restrict__ x3, const float* __restrict__ ff,
    float* __restrict__ out)
{
    __shared__ float y2s[32][64];   // 8 KiB
    __shared__ float y3s[2][64];    // 512 B

    const int bid = blockIdx.x;
    const int b   = bid >> 6;       // 0..7
    const int h   = bid & 63;       // output row 0..63
    const int tid = threadIdx.x;

    // ---- Phase 1: y3 row (2 ch x 64 w), each = max over 8x8 window of x3 ----
    if (tid < 128) {
        const int c3 = tid >> 6;    // 0..1
        const int w  = tid & 63;
        const float* p = x3 + (size_t)b * 524288 + (size_t)c3 * 262144
                            + (size_t)(h * 8) * 512 + (size_t)w * 8;
        float m = -INFINITY;
        #pragma unroll
        for (int r = 0; r < 8; ++r) {
            const float4 a = *reinterpret_cast<const float4*>(p + (size_t)r * 512);
            const float4 c = *reinterpret_cast<const float4*>(p + (size_t)r * 512 + 4);
            m = fmaxf(m, fmaxf(fmaxf(fmaxf(a.x, a.y), fmaxf(a.z, a.w)),
                               fmaxf(fmaxf(c.x, c.y), fmaxf(c.z, c.w))));
        }
        y3s[c3][w] = m;
    }

    // ---- Phase 2: y2 row (32 ch x 64 w), each = max over 4x4 window of x2 ----
    #pragma unroll
    for (int v = tid; v < 2048; v += 256) {
        const int c2 = v >> 6;      // 0..31
        const int w  = v & 63;
        const float* p = x2 + (size_t)b * 2097152 + (size_t)c2 * 65536
                            + (size_t)(h * 4) * 256 + (size_t)w * 4;
        float m = -INFINITY;
        #pragma unroll
        for (int r = 0; r < 4; ++r) {
            const float4 a = *reinterpret_cast<const float4*>(p + (size_t)r * 256);
            m = fmaxf(m, fmaxf(fmaxf(a.x, a.y), fmaxf(a.z, a.w)));
        }
        y2s[c2][w] = m;
    }

    __syncthreads();

    // ---- Phase 3: 2x2 pool of x1 in regs; combine + relu; write c1 and c1+128 ----
    const int w     = tid & 63;
    const int clane = tid >> 6;     // 0..3
    #pragma unroll 4
    for (int it = 0; it < 32; ++it) {
        const int c1 = it * 4 + clane;    // 0..127
        const float* p = x1 + (size_t)b * 2097152 + (size_t)c1 * 16384
                            + (size_t)(h * 2) * 128 + (size_t)w * 2;
        const float2 a  = *reinterpret_cast<const float2*>(p);
        const float2 bb = *reinterpret_cast<const float2*>(p + 128);
        const float p1 = fmaxf(fmaxf(a.x, a.y), fmaxf(bb.x, bb.y));
        const float s  = p1 + y2s[c1 & 31][w] + y3s[c1 & 1][w];

        const size_t obase = (size_t)b * 1048576 + (size_t)h * 64 + (size_t)w;
        const size_t o0 = obase + (size_t)c1 * 4096;
        const size_t o1 = obase + (size_t)(c1 + 128) * 4096;
        __builtin_nontemporal_store(fmaxf(s + ff[o0], 0.0f), out + o0);
        __builtin_nontemporal_store(fmaxf(s + ff[o1], 0.0f), out + o1);
    }
}

extern "C" void kernel_launch(void* const* d_in, const int* in_sizes, int n_in,
                              void* d_out, int out_size, void* d_ws, size_t ws_size,
                              hipStream_t stream) {
    const float* x1 = (const float*)d_in[0];
    const float* x2 = (const float*)d_in[1];
    const float* x3 = (const float*)d_in[2];
    const float* ff = (const float*)d_in[3];
    float* out = (float*)d_out;

    dim3 grid(512);   // 8 batches * 64 output rows
    dim3 block(256);
    fused_ff_block3<<<grid, block, 0, stream>>>(x1, x2, x3, ff, out);
}